// Round 1
// baseline (26043.744 us; speedup 1.0000x reference)
//
#include <hip/hip_runtime.h>
#include <math.h>

// Speller: attention-LSTM -> LSTM1 -> LSTM2 -> dense+softmax, all fp32.
// Round 0: correctness-first baseline.
//   - 3 big input GEMMs done as parallel kernels (ZY = y@W_a etc.)
//   - recurrences: one workgroup per batch (32 WGs x 1024 thr), block syncs only.
//     Each WG streams R (4 MB) per step -> expected L2/L3 bound; this round
//     measures that so round 1 can pick slice/LDS-resident or MFMA designs.

#define U_   512
#define S_   512
#define T_   128
#define B_   32
#define G4   2048   // 4*U
#define V_   46

__device__ __forceinline__ float sigmoidf_(float x) {
  return 1.0f / (1.0f + expf(-x));
}

// ---------------- GEMM: Z[M,2048] = A[M,512] @ W[512,2048] + b ----------------
// M = 4096 (B*T). Block 256 threads, each thread: 8 rows x 4 cols.
// grid = (2048/1024, 4096/8) = (2, 512). A-row reads are block-uniform
// (compiler scalarizes to s_load); W reads are coalesced float4.
__global__ __launch_bounds__(256) void gemm_k512(
    const float* __restrict__ A, const float* __restrict__ W,
    const float* __restrict__ b, float* __restrict__ Z) {
  const int tid = threadIdx.x;
  const int j = blockIdx.x * 1024 + tid * 4;
  const int i0 = blockIdx.y * 8;
  float4 bj = *(const float4*)(b + j);
  float4 acc[8];
#pragma unroll
  for (int r = 0; r < 8; ++r) acc[r] = bj;
  const float* Arow = A + (size_t)i0 * U_;
  for (int k = 0; k < U_; ++k) {
    float4 w = *(const float4*)(W + (size_t)k * G4 + j);
#pragma unroll
    for (int r = 0; r < 8; ++r) {
      float a = Arow[(size_t)r * U_ + k];   // uniform across block
      acc[r].x = fmaf(a, w.x, acc[r].x);
      acc[r].y = fmaf(a, w.y, acc[r].y);
      acc[r].z = fmaf(a, w.z, acc[r].z);
      acc[r].w = fmaf(a, w.w, acc[r].w);
    }
  }
#pragma unroll
  for (int r = 0; r < 8; ++r)
    *(float4*)(Z + (size_t)(i0 + r) * G4 + j) = acc[r];
}

// ---------------- attention LSTM: one WG per batch ----------------
// carries (h+ctx, c+ctx); emits ctx per step.
__global__ __launch_bounds__(1024) void attn_lstm_k(
    const float* __restrict__ x,    // [B][S][U]
    const float* __restrict__ ZY,   // [B][T][4U] = y@W_a + b_a
    const float* __restrict__ R,    // [U][4U]
    float* __restrict__ ctxs) {     // [B][T][U]
  const int b = blockIdx.x;
  const int tid = threadIdx.x;
  const int lane = tid & 63;
  const int wave = tid >> 6;
  __shared__ __align__(16) float h_s[U_];
  __shared__ float hn_s[U_];
  __shared__ float z_s[G4];
  __shared__ float p_s[S_];
  __shared__ float cp_s[2][U_];
  __shared__ float red_s[16];
  float c = 0.f;
  for (int i = tid; i < U_; i += 1024) h_s[i] = 0.f;
  __syncthreads();
  const float* xb = x + (size_t)b * S_ * U_;

  for (int t = 0; t < T_; ++t) {
    // 1. z = ZY[b][t] + h @ R   (each thread: 2 adjacent cols)
    {
      const float* zrow = ZY + ((size_t)b * T_ + t) * G4;
      const int j = tid * 2;
      float a0 = zrow[j], a1 = zrow[j + 1];
      const float* Rp = R + j;
#pragma unroll 4
      for (int k = 0; k < U_; ++k) {
        float hk = h_s[k];
        float2 w = *(const float2*)(Rp + (size_t)k * G4);
        a0 = fmaf(hk, w.x, a0);
        a1 = fmaf(hk, w.y, a1);
      }
      z_s[j] = a0; z_s[j + 1] = a1;
    }
    __syncthreads();
    // 2. gates (i,f,g,o) -> c_new, hn
    if (tid < U_) {
      float ig = sigmoidf_(z_s[tid]);
      float fg = sigmoidf_(z_s[U_ + tid]);
      float gg = tanhf(z_s[2 * U_ + tid]);
      float og = sigmoidf_(z_s[3 * U_ + tid]);
      c = fg * c + ig * gg;
      hn_s[tid] = og * tanhf(c);
    }
    __syncthreads();
    // 3. scores[s] = hn . x[b][s][:]  (wave handles 32 s, lane-parallel over k)
    for (int si = 0; si < 32; ++si) {
      const int s = wave * 32 + si;
      const float* xr = xb + (size_t)s * U_;
      float acc = 0.f;
#pragma unroll
      for (int k = lane; k < U_; k += 64) acc = fmaf(hn_s[k], xr[k], acc);
#pragma unroll
      for (int off = 32; off; off >>= 1) acc += __shfl_down(acc, off);
      if (lane == 0) p_s[s] = acc;
    }
    __syncthreads();
    // 4. softmax over 512 scores
    float v = (tid < S_) ? p_s[tid] : -INFINITY;
    float m = v;
#pragma unroll
    for (int off = 32; off; off >>= 1) m = fmaxf(m, __shfl_down(m, off));
    if (lane == 0) red_s[wave] = m;
    __syncthreads();
    if (wave == 0) {
      float w2 = (lane < 16) ? red_s[lane] : -INFINITY;
#pragma unroll
      for (int off = 8; off; off >>= 1) w2 = fmaxf(w2, __shfl_down(w2, off));
      if (lane == 0) red_s[0] = w2;
    }
    __syncthreads();
    const float m_all = red_s[0];
    float ex = (tid < S_) ? expf(v - m_all) : 0.f;
    if (tid < S_) p_s[tid] = ex;          // unnormalized
    float ssum = ex;
#pragma unroll
    for (int off = 32; off; off >>= 1) ssum += __shfl_down(ssum, off);
    __syncthreads();                       // red_s reuse + p_s visibility
    if (lane == 0) red_s[wave] = ssum;
    __syncthreads();
    if (wave == 0) {
      float w2 = (lane < 16) ? red_s[lane] : 0.f;
#pragma unroll
      for (int off = 8; off; off >>= 1) w2 += __shfl_down(w2, off);
      if (lane == 0) red_s[0] = w2;
    }
    __syncthreads();
    const float inv = 1.0f / red_s[0];
    // 5. ctx[u] = sum_s p[s] x[b][s][u]  (two halves over s)
    {
      const int u = tid & (U_ - 1);
      const int half = tid >> 9;
      const float* xp = xb + (size_t)half * 256 * U_ + u;
      const float* pp = p_s + half * 256;
      float acc = 0.f;
#pragma unroll 4
      for (int s = 0; s < 256; ++s) acc = fmaf(pp[s], xp[(size_t)s * U_], acc);
      cp_s[half][u] = acc;
    }
    __syncthreads();
    if (tid < U_) {
      float ctxv = (cp_s[0][tid] + cp_s[1][tid]) * inv;
      ctxs[((size_t)b * T_ + t) * U_ + tid] = ctxv;
      h_s[tid] = hn_s[tid] + ctxv;   // carry = h + ctx
      c += ctxv;                     // carry = c + ctx
    }
    __syncthreads();
  }
}

// ---------------- plain LSTM recurrence: one WG per batch ----------------
__global__ __launch_bounds__(1024) void lstm_seq_k(
    const float* __restrict__ Zin,  // [B][T][4U] = input@W + b
    const float* __restrict__ R,    // [U][4U]
    float* __restrict__ seq_out,    // [B][T][U] or null
    float* __restrict__ last_out) { // [B][U] or null
  const int b = blockIdx.x;
  const int tid = threadIdx.x;
  __shared__ __align__(16) float h_s[U_];
  __shared__ float z_s[G4];
  float c = 0.f;
  for (int i = tid; i < U_; i += 1024) h_s[i] = 0.f;
  __syncthreads();
  for (int t = 0; t < T_; ++t) {
    {
      const float* zrow = Zin + ((size_t)b * T_ + t) * G4;
      const int j = tid * 2;
      float a0 = zrow[j], a1 = zrow[j + 1];
      const float* Rp = R + j;
#pragma unroll 4
      for (int k = 0; k < U_; ++k) {
        float hk = h_s[k];
        float2 w = *(const float2*)(Rp + (size_t)k * G4);
        a0 = fmaf(hk, w.x, a0);
        a1 = fmaf(hk, w.y, a1);
      }
      z_s[j] = a0; z_s[j + 1] = a1;
    }
    __syncthreads();
    if (tid < U_) {
      float ig = sigmoidf_(z_s[tid]);
      float fg = sigmoidf_(z_s[U_ + tid]);
      float gg = tanhf(z_s[2 * U_ + tid]);
      float og = sigmoidf_(z_s[3 * U_ + tid]);
      c = fg * c + ig * gg;
      float hv = og * tanhf(c);
      h_s[tid] = hv;
      if (seq_out) seq_out[((size_t)b * T_ + t) * U_ + tid] = hv;
    }
    __syncthreads();
  }
  if (last_out && tid < U_) last_out[(size_t)b * U_ + tid] = h_s[tid];
}

// ---------------- decoder: softmax(hT @ Wd + bd) ----------------
__global__ __launch_bounds__(64) void final_k(
    const float* __restrict__ hT, const float* __restrict__ Wd,
    const float* __restrict__ bd, float* __restrict__ out) {
  const int b = blockIdx.x;
  const int v = threadIdx.x;
  float acc = (v < V_) ? bd[v] : -INFINITY;
  if (v < V_) {
    for (int k = 0; k < U_; ++k)
      acc = fmaf(hT[(size_t)b * U_ + k], Wd[(size_t)k * V_ + v], acc);
  }
  float m = acc;
#pragma unroll
  for (int off = 32; off; off >>= 1) m = fmaxf(m, __shfl_down(m, off));
  m = __shfl(m, 0);
  float e = (v < V_) ? expf(acc - m) : 0.f;
  float s = e;
#pragma unroll
  for (int off = 32; off; off >>= 1) s += __shfl_down(s, off);
  s = __shfl(s, 0);
  if (v < V_) out[(size_t)b * V_ + v] = e / s;
}

extern "C" void kernel_launch(void* const* d_in, const int* in_sizes, int n_in,
                              void* d_out, int out_size, void* d_ws, size_t ws_size,
                              hipStream_t stream) {
  const float* x   = (const float*)d_in[0];   // [32,512,512]
  const float* y   = (const float*)d_in[1];   // [32,128,512]
  const float* W_a = (const float*)d_in[2];
  const float* R_a = (const float*)d_in[3];
  const float* b_a = (const float*)d_in[4];
  const float* W1  = (const float*)d_in[5];
  const float* R1  = (const float*)d_in[6];
  const float* b1  = (const float*)d_in[7];
  const float* W2  = (const float*)d_in[8];
  const float* R2  = (const float*)d_in[9];
  const float* b2  = (const float*)d_in[10];
  const float* Wd  = (const float*)d_in[11];
  const float* bd  = (const float*)d_in[12];
  float* out = (float*)d_out;

  // workspace layout (floats): ZBUF 4096*2048, SEQ 4096*512, HT 32*512
  float* ZBUF = (float*)d_ws;                 // reused: ZY -> Z1 -> Z2
  float* SEQ  = ZBUF + (size_t)4096 * 2048;   // reused: ctxs -> hs1
  float* HT   = SEQ + (size_t)4096 * 512;

  dim3 ggrid(2, 512);
  // 1. ZY = y @ W_a + b_a
  gemm_k512<<<ggrid, 256, 0, stream>>>(y, W_a, b_a, ZBUF);
  // 2. attention LSTM -> ctxs
  attn_lstm_k<<<B_, 1024, 0, stream>>>(x, ZBUF, R_a, SEQ);
  // 3. Z1 = ctxs @ W1 + b1
  gemm_k512<<<ggrid, 256, 0, stream>>>(SEQ, W1, b1, ZBUF);
  // 4. LSTM1 -> hs1 (overwrites SEQ; ctxs already consumed)
  lstm_seq_k<<<B_, 1024, 0, stream>>>(ZBUF, R1, SEQ, nullptr);
  // 5. Z2 = hs1 @ W2 + b2
  gemm_k512<<<ggrid, 256, 0, stream>>>(SEQ, W2, b2, ZBUF);
  // 6. LSTM2 -> hT only
  lstm_seq_k<<<B_, 1024, 0, stream>>>(ZBUF, R2, nullptr, HT);
  // 7. decode + softmax
  final_k<<<B_, 64, 0, stream>>>(HT, Wd, bd, out);
}

// Round 2
// 17728.287 us; speedup vs baseline: 1.4691x; 1.4691x over previous
//
#include <hip/hip_runtime.h>
#include <math.h>

// Speller round 1: cooperative persistent recurrences.
//  - R (4 MB) sliced 16 KB/WG into LDS, loaded once; batched GEMV over all 32
//    batches per step across 256 WGs (1/CU).
//  - x (32 MB) fully LDS-resident across the grid for attention (137 KB/WG).
//  - hand-rolled device-scope grid barrier (monotonic seq, agent-scope atomics
//    + __threadfence for cross-XCD visibility). attention: 3 barriers/step
//    (flash-style local-max softmax combine), plain LSTM: 1 barrier/step.
//  - h stored transposed [k/4][b][4] so global<->LDS staging is coalesced.

#define U_   512
#define S_   512
#define T_   128
#define B_   32
#define G4   2048
#define V_   46
#define NWG  256

__device__ __forceinline__ void grid_bar(unsigned* cnt, unsigned* gen,
                                         unsigned seq, unsigned nwg) {
  __syncthreads();
  if (threadIdx.x == 0) {
    __threadfence();
    unsigned prev = atomicAdd(cnt, 1u);
    if (prev == seq * nwg - 1u) {
      __hip_atomic_store(gen, seq, __ATOMIC_RELEASE, __HIP_MEMORY_SCOPE_AGENT);
    } else {
      while (__hip_atomic_load(gen, __ATOMIC_ACQUIRE, __HIP_MEMORY_SCOPE_AGENT) < seq) {
        __builtin_amdgcn_s_sleep(1);
      }
    }
    __threadfence();
  }
  __syncthreads();
}

// ---------------- GEMM: Z[M,2048] = A[M,512] @ W[512,2048] + b ----------------
__global__ __launch_bounds__(256) void gemm_k512(
    const float* __restrict__ A, const float* __restrict__ W,
    const float* __restrict__ b, float* __restrict__ Z) {
  const int tid = threadIdx.x;
  const int j = blockIdx.x * 1024 + tid * 4;
  const int i0 = blockIdx.y * 8;
  float4 bj = *(const float4*)(b + j);
  float4 acc[8];
#pragma unroll
  for (int r = 0; r < 8; ++r) acc[r] = bj;
  const float* Arow = A + (size_t)i0 * U_;
  for (int k = 0; k < U_; ++k) {
    float4 w = *(const float4*)(W + (size_t)k * G4 + j);
#pragma unroll
    for (int r = 0; r < 8; ++r) {
      float a = Arow[(size_t)r * U_ + k];
      acc[r].x = fmaf(a, w.x, acc[r].x);
      acc[r].y = fmaf(a, w.y, acc[r].y);
      acc[r].z = fmaf(a, w.z, acc[r].z);
      acc[r].w = fmaf(a, w.w, acc[r].w);
    }
  }
#pragma unroll
  for (int r = 0; r < 8; ++r)
    *(float4*)(Z + (size_t)(i0 + r) * G4 + j) = acc[r];
}

// ---------------- attention LSTM, cooperative ----------------
// grid 256 x 512 thr. WG bid: GEMV role owns units {2*bid, 2*bid+1};
// attention role owns (batch bid>>3, seq rows 64*(bid&7) .. +63).
// dynamic LDS: x_s [512][67] (137216 B) + R_s [8][512] (16384 B).
__global__ __launch_bounds__(512) void attn_coop(
    const float* __restrict__ x, const float* __restrict__ ZY,
    const float* __restrict__ R, float* __restrict__ ctxs,
    float* __restrict__ hbuf, float* __restrict__ hnbuf,
    float* __restrict__ smax, float* __restrict__ ssumg,
    float* __restrict__ ctxpart, unsigned* cnt, unsigned* gen) {
  extern __shared__ float dyn[];
  float* x_s = dyn;                    // [u][67] padded (2-way banks only)
  float* R_s = dyn + 512 * 67;         // [cg][512]
  __shared__ float zp[32][8][2];
  __shared__ float hn_s[512];
  __shared__ float p_s[64];

  const int tid = threadIdx.x;
  const int bid = blockIdx.x;
  const int u0 = bid * 2;
  const int b_g = tid & 31;            // GEMV batch lane
  const int cg  = (tid >> 5) & 7;      // col group: g*2+du
  const int kh  = tid >> 8;            // k half
  const int battn = bid >> 3;
  const int sc = bid & 7;

  // one-time: x slice into LDS (coalesced global, 2-way LDS banks)
  for (int idx = tid; idx < 64 * 512; idx += 512) {
    int sl = idx >> 9, u = idx & 511;
    x_s[u * 67 + sl] = x[((size_t)battn * S_ + sc * 64 + sl) * U_ + u];
  }
  // one-time: R slice into LDS
  for (int idx = tid; idx < 4096; idx += 512) {
    int k = idx >> 3, c8 = idx & 7, g = c8 >> 1, du = c8 & 1;
    R_s[c8 * 512 + k] = R[(size_t)k * G4 + g * 512 + u0 + du];
  }
  float c = 0.f, hn_reg = 0.f;
  unsigned seq = 0;
  __syncthreads();

  for (int t = 0; t < T_; ++t) {
    // ---- phase A: z = ZY + h@R, gates, hn ----
    {
      const float4* hb4 = (const float4*)(hbuf + (t & 1) * 16384);
      const float4* R4 = (const float4*)(R_s + cg * 512);
      float acc = 0.f;
      const int k40 = kh * 64;
#pragma unroll 8
      for (int k4 = 0; k4 < 64; ++k4) {
        float4 hv = hb4[(k40 + k4) * 32 + b_g];
        float4 rv = R4[k40 + k4];
        acc = fmaf(hv.x, rv.x, acc); acc = fmaf(hv.y, rv.y, acc);
        acc = fmaf(hv.z, rv.z, acc); acc = fmaf(hv.w, rv.w, acc);
      }
      zp[b_g][cg][kh] = acc;
    }
    __syncthreads();
    if (tid < 64) {
      const int b = tid >> 1, du = tid & 1;
      const float* zy = ZY + ((size_t)b * T_ + t) * G4 + u0 + du;
      float zi = zy[0]    + zp[b][0 + du][0] + zp[b][0 + du][1];
      float zf = zy[512]  + zp[b][2 + du][0] + zp[b][2 + du][1];
      float zg = zy[1024] + zp[b][4 + du][0] + zp[b][4 + du][1];
      float zo = zy[1536] + zp[b][6 + du][0] + zp[b][6 + du][1];
      float ig = 1.f / (1.f + expf(-zi));
      float fg = 1.f / (1.f + expf(-zf));
      float gg = tanhf(zg);
      float og = 1.f / (1.f + expf(-zo));
      c = fg * c + ig * gg;
      hn_reg = og * tanhf(c);
      hnbuf[b * 512 + u0 + du] = hn_reg;
    }
    grid_bar(cnt, gen, ++seq, NWG);

    // ---- phase B+C: scores, local softmax, ctx partials ----
    if (tid < 128)
      ((float4*)hn_s)[tid] = ((const float4*)(hnbuf + battn * 512))[tid];
    __syncthreads();
    {
      const int wv = tid >> 6, ln = tid & 63;
      for (int si = 0; si < 8; ++si) {
        const int sl = wv * 8 + si;
        float a = 0.f;
#pragma unroll
        for (int uu = ln; uu < 512; uu += 64)
          a = fmaf(hn_s[uu], x_s[uu * 67 + sl], a);
#pragma unroll
        for (int off = 32; off; off >>= 1) a += __shfl_down(a, off);
        if (ln == 0) p_s[sl] = a;
      }
    }
    __syncthreads();
    if (tid < 64) {
      float v = p_s[tid];
      float m = v;
#pragma unroll
      for (int off = 32; off; off >>= 1) m = fmaxf(m, __shfl_down(m, off));
      m = __shfl(m, 0);
      float ex = expf(v - m);
      p_s[tid] = ex;
      float sm = ex;
#pragma unroll
      for (int off = 32; off; off >>= 1) sm += __shfl_down(sm, off);
      if (tid == 0) { smax[battn * 8 + sc] = m; ssumg[battn * 8 + sc] = sm; }
    }
    __syncthreads();
    {
      float a = 0.f;
      const float* xr = x_s + tid * 67;
#pragma unroll 8
      for (int s = 0; s < 64; ++s) a = fmaf(p_s[s], xr[s], a);
      ctxpart[((size_t)battn * 8 + sc) * 512 + tid] = a;
    }
    grid_bar(cnt, gen, ++seq, NWG);

    // ---- phase D: combine slices, update carries ----
    if (tid < 64) {
      const int b = tid >> 1, du = tid & 1, u = u0 + du;
      float lm[8], gm = -INFINITY;
#pragma unroll
      for (int j = 0; j < 8; ++j) { lm[j] = smax[b * 8 + j]; gm = fmaxf(gm, lm[j]); }
      float stot = 0.f, cs = 0.f;
#pragma unroll
      for (int j = 0; j < 8; ++j) {
        float w = expf(lm[j] - gm);
        stot = fmaf(ssumg[b * 8 + j], w, stot);
        cs = fmaf(ctxpart[((size_t)b * 8 + j) * 512 + u], w, cs);
      }
      float ctxv = cs / stot;
      c += ctxv;
      float hcar = hn_reg + ctxv;
      hbuf[((t + 1) & 1) * 16384 + ((u >> 2) * 32 + b) * 4 + (u & 3)] = hcar;
      ctxs[((size_t)b * T_ + t) * U_ + u] = ctxv;
    }
    grid_bar(cnt, gen, ++seq, NWG);
  }
}

// ---------------- plain LSTM, cooperative ----------------
// grid 256 x 512. dynamic LDS: h_s 64 KB + R_s 16 KB.
__global__ __launch_bounds__(512) void lstm_coop(
    const float* __restrict__ Zin, const float* __restrict__ R,
    float* __restrict__ seq_out, float* __restrict__ last_out,
    float* __restrict__ hbuf, unsigned* cnt, unsigned* gen) {
  extern __shared__ float dyn[];
  float* h_s = dyn;                    // [k4][b][4] = 16384 floats
  float* R_s = dyn + 16384;            // [cg][512]
  __shared__ float zp[32][8][2];
  const int tid = threadIdx.x;
  const int bid = blockIdx.x;
  const int u0 = bid * 2;
  const int b_g = tid & 31, cg = (tid >> 5) & 7, kh = tid >> 8;

  for (int idx = tid; idx < 4096; idx += 512) {
    int k = idx >> 3, c8 = idx & 7, g = c8 >> 1, du = c8 & 1;
    R_s[c8 * 512 + k] = R[(size_t)k * G4 + g * 512 + u0 + du];
  }
  float c = 0.f;
  unsigned seq = 0;
  __syncthreads();

  for (int t = 0; t < T_; ++t) {
    {
      const float4* hb4 = (const float4*)(hbuf + (t & 1) * 16384);
      float4* hs4 = (float4*)h_s;
      for (int i = tid; i < 4096; i += 512) hs4[i] = hb4[i];
    }
    __syncthreads();
    {
      const float4* H4 = (const float4*)h_s;
      const float4* R4 = (const float4*)(R_s + cg * 512);
      float acc = 0.f;
      const int k40 = kh * 64;
#pragma unroll 8
      for (int k4 = 0; k4 < 64; ++k4) {
        float4 hv = H4[(k40 + k4) * 32 + b_g];
        float4 rv = R4[k40 + k4];
        acc = fmaf(hv.x, rv.x, acc); acc = fmaf(hv.y, rv.y, acc);
        acc = fmaf(hv.z, rv.z, acc); acc = fmaf(hv.w, rv.w, acc);
      }
      zp[b_g][cg][kh] = acc;
    }
    __syncthreads();
    if (tid < 64) {
      const int b = tid >> 1, du = tid & 1, u = u0 + du;
      const float* zy = Zin + ((size_t)b * T_ + t) * G4 + u0 + du;
      float zi = zy[0]    + zp[b][0 + du][0] + zp[b][0 + du][1];
      float zf = zy[512]  + zp[b][2 + du][0] + zp[b][2 + du][1];
      float zg = zy[1024] + zp[b][4 + du][0] + zp[b][4 + du][1];
      float zo = zy[1536] + zp[b][6 + du][0] + zp[b][6 + du][1];
      float ig = 1.f / (1.f + expf(-zi));
      float fg = 1.f / (1.f + expf(-zf));
      float gg = tanhf(zg);
      float og = 1.f / (1.f + expf(-zo));
      c = fg * c + ig * gg;
      float hv2 = og * tanhf(c);
      hbuf[((t + 1) & 1) * 16384 + ((u >> 2) * 32 + b) * 4 + (u & 3)] = hv2;
      if (seq_out) seq_out[((size_t)b * T_ + t) * U_ + u] = hv2;
      if (last_out && t == T_ - 1) last_out[b * U_ + u] = hv2;
    }
    grid_bar(cnt, gen, ++seq, NWG);
  }
}

// ---------------- decoder ----------------
__global__ __launch_bounds__(64) void final_k(
    const float* __restrict__ hT, const float* __restrict__ Wd,
    const float* __restrict__ bd, float* __restrict__ out) {
  const int b = blockIdx.x;
  const int v = threadIdx.x;
  float acc = (v < V_) ? bd[v] : -INFINITY;
  if (v < V_) {
    for (int k = 0; k < U_; ++k)
      acc = fmaf(hT[(size_t)b * U_ + k], Wd[(size_t)k * V_ + v], acc);
  }
  float m = acc;
#pragma unroll
  for (int off = 32; off; off >>= 1) m = fmaxf(m, __shfl_down(m, off));
  m = __shfl(m, 0);
  float e = (v < V_) ? expf(acc - m) : 0.f;
  float s = e;
#pragma unroll
  for (int off = 32; off; off >>= 1) s += __shfl_down(s, off);
  s = __shfl(s, 0);
  if (v < V_) out[(size_t)b * V_ + v] = e / s;
}

extern "C" void kernel_launch(void* const* d_in, const int* in_sizes, int n_in,
                              void* d_out, int out_size, void* d_ws, size_t ws_size,
                              hipStream_t stream) {
  const float* x   = (const float*)d_in[0];
  const float* y   = (const float*)d_in[1];
  const float* W_a = (const float*)d_in[2];
  const float* R_a = (const float*)d_in[3];
  const float* b_a = (const float*)d_in[4];
  const float* W1  = (const float*)d_in[5];
  const float* R1  = (const float*)d_in[6];
  const float* b1  = (const float*)d_in[7];
  const float* W2  = (const float*)d_in[8];
  const float* R2  = (const float*)d_in[9];
  const float* b2  = (const float*)d_in[10];
  const float* Wd  = (const float*)d_in[11];
  const float* bd  = (const float*)d_in[12];
  float* out = (float*)d_out;

  // workspace (floats)
  float* ZBUF = (float*)d_ws;                    // 8388608
  float* SEQ  = ZBUF + (size_t)8388608;          // 2097152
  float* SCR  = SEQ + (size_t)2097152;
  unsigned* CNT = (unsigned*)SCR;                // 16 slots
  float* HBUF = SCR + 16;                        // 2*16384
  float* HN   = HBUF + 32768;                    // 16384
  float* SMAX = HN + 16384;                      // 256
  float* SSUM = SMAX + 256;                      // 256
  float* CTXP = SSUM + 256;                      // 131072
  float* HT   = CTXP + 131072;                   // 16384

  const int attn_lds = (512 * 67 + 8 * 512) * 4;   // 153600 B
  const int lstm_lds = (16384 + 4096) * 4;          // 81920 B
  hipFuncSetAttribute((const void*)attn_coop,
                      hipFuncAttributeMaxDynamicSharedMemorySize, attn_lds);
  hipFuncSetAttribute((const void*)lstm_coop,
                      hipFuncAttributeMaxDynamicSharedMemorySize, lstm_lds);

  dim3 ggrid(2, 512);
  hipMemsetAsync(CNT, 0, 64, stream);

  // 1. ZY = y @ W_a + b_a
  gemm_k512<<<ggrid, 256, 0, stream>>>(y, W_a, b_a, ZBUF);
  // 2. attention LSTM -> ctxs (SEQ)
  hipMemsetAsync(HBUF, 0, 16384 * 4, stream);
  attn_coop<<<NWG, 512, attn_lds, stream>>>(x, ZBUF, R_a, SEQ, HBUF, HN,
                                            SMAX, SSUM, CTXP, CNT + 0, CNT + 1);
  // 3. Z1 = ctxs @ W1 + b1
  gemm_k512<<<ggrid, 256, 0, stream>>>(SEQ, W1, b1, ZBUF);
  // 4. LSTM1 -> hs1 (SEQ)
  hipMemsetAsync(HBUF, 0, 16384 * 4, stream);
  lstm_coop<<<NWG, 512, lstm_lds, stream>>>(ZBUF, R1, SEQ, nullptr, HBUF,
                                            CNT + 2, CNT + 3);
  // 5. Z2 = hs1 @ W2 + b2
  gemm_k512<<<ggrid, 256, 0, stream>>>(SEQ, W2, b2, ZBUF);
  // 6. LSTM2 -> hT
  hipMemsetAsync(HBUF, 0, 16384 * 4, stream);
  lstm_coop<<<NWG, 512, lstm_lds, stream>>>(ZBUF, R2, nullptr, HT, HBUF,
                                            CNT + 4, CNT + 5);
  // 7. decode
  final_k<<<B_, 64, 0, stream>>>(HT, Wd, bd, out);
}